// Round 7
// baseline (828.049 us; speedup 1.0000x reference)
//
#include <hip/hip_runtime.h>
#include <hip/hip_cooperative_groups.h>
#include <math.h>

namespace cg = cooperative_groups;

// Problem constants
#define B_ 2
#define T_ 1024
#define D_ 512
#define H_ 8
#define DK_ 64
#define NBH_ 16          // B*H
#define C_ 32            // chunk length
#define G_ 32            // T/C chunks

#define PI_OVER_2T 0.00153398078788564122971808758949f  /* pi/2048 */

typedef float f32x4 __attribute__((ext_vector_type(4)));
typedef short s16x8 __attribute__((ext_vector_type(8)));

__device__ __forceinline__ ushort f2bf(float x) {
    unsigned u = __float_as_uint(x);
    unsigned r = (u + 0x7fffu + ((u >> 16) & 1u)) >> 16;   // RNE
    return (ushort)r;
}
__device__ __forceinline__ float bf2f(ushort u) {
    return __uint_as_float((unsigned)u << 16);
}
__device__ __forceinline__ s16x8 bscale(s16x8 v, float s) {
    s16x8 r;
#pragma unroll
    for (int u = 0; u < 8; u++)
        r[u] = (short)f2bf(bf2f((ushort)v[u]) * s);
    return r;
}

// async global->LDS, 16B/lane; LDS dest must be tid-contiguous (m104).
__device__ __forceinline__ void async16(void* lds, const void* g) {
    __builtin_amdgcn_global_load_lds(
        (const __attribute__((address_space(1))) void*)g,
        (__attribute__((address_space(3))) void*)lds, 16, 0, 0);
}

// ---------------------------------------------------------------------------
// Shared-memory phase layouts (union in the mega kernel)
// ---------------------------------------------------------------------------
struct SmemCv { float Ts[64][65]; };                                  // 16.6 KB
struct SmemG0 { ushort As[2 * 128 * 64]; ushort Bs[2 * 64 * 64]; };   // 48 KB
struct SmemKV { ushort KcT[64 * 40]; ushort KsT[64 * 40]; ushort VT[64 * 40]; };
struct SmemOC { ushort VT[64 * 40]; ushort Pb[32 * 40]; float zinv[32]; };
struct SmemG1 { ushort As[2 * 64 * 64]; ushort Bs[2 * 32 * 64]; };    // 24 KB
union SmemU { SmemCv cv; SmemG0 g0; SmemKV kv; SmemOC oc; SmemG1 g1; };

// ---------------------------------------------------------------------------
// Phase bodies (shared by standalone kernels and the mega kernel)
// ---------------------------------------------------------------------------

// conv unit u: 0..1023 x->bf16; 1024..1343 weight transpose (mi=unit>>6)
__device__ __forceinline__ void conv_body(
    int u, int tid, const float* __restrict__ x,
    const float* __restrict__ Wq, const float* __restrict__ Wk,
    const float* __restrict__ Wv, const float* __restrict__ Wg,
    const float* __restrict__ Wo,
    ushort* __restrict__ xb, ushort* __restrict__ WtAll, SmemCv& sm)
{
    if (u < 1024) {
        int i = (u * 256 + tid) * 4;
        float4 v = *(const float4*)&x[i];
        ushort4 o;
        o.x = f2bf(v.x); o.y = f2bf(v.y); o.z = f2bf(v.z); o.w = f2bf(v.w);
        *(ushort4*)&xb[i] = o;
        return;
    }
    const int bid = u - 1024;
    const int mi = bid >> 6;
    const int t64 = bid & 63;
    const float* __restrict__ W = (mi == 0) ? Wq : (mi == 1) ? Wk
                                 : (mi == 2) ? Wv : (mi == 3) ? Wg : Wo;
    const int tr = t64 >> 3, tc = t64 & 7;
#pragma unroll
    for (int p = 0; p < 4; p++) {
        int row = p * 16 + (tid >> 4);
        int c4 = (tid & 15) * 4;
        float4 v = *(const float4*)&W[(size_t)(tr * 64 + row) * 512 + tc * 64 + c4];
        sm.Ts[row][c4 + 0] = v.x; sm.Ts[row][c4 + 1] = v.y;
        sm.Ts[row][c4 + 2] = v.z; sm.Ts[row][c4 + 3] = v.w;
    }
    __syncthreads();
    const int nl = tid >> 2, kc = (tid & 3) * 16;
    ushort buf[16];
#pragma unroll
    for (int uu = 0; uu < 16; uu++) buf[uu] = f2bf(sm.Ts[kc + uu][nl]);
    ushort* dst = WtAll + (size_t)mi * 262144 + (size_t)(tc * 64 + nl) * 512
                  + tr * 64 + kc;
    *(uint4*)dst = *(uint4*)&buf[0];
    *(uint4*)(dst + 8) = *(uint4*)&buf[8];
}

// bf16 MFMA GEMM tile, double-buffered K-loop, XOR chunk swizzle (2-way free).
// MODE 0: wb decodes 32 ct x 16 row-tiles (TM=128,TN=64); bf16 outs + act.
// MODE 1: wb decodes 16 ct x 32 row-tiles (TM=64,TN=32); f32 out.
template<int MODE, int TM, int TN, int BK>
__device__ __forceinline__ void gemm_body(
    int wb, int tid,
    const ushort* __restrict__ A, const ushort* __restrict__ Bt,
    const float* __restrict__ bg,
    void* __restrict__ O0v, void* __restrict__ O1v,
    void* __restrict__ O2v, void* __restrict__ O3v,
    ushort* __restrict__ AsB, ushort* __restrict__ BsB)
{
    constexpr int WM = TM / 2, WN = TN / 2;
    constexpr int FM = WM / 16, FN = WN / 16;
    constexpr int CH = BK / 8;
    constexpr int SH = (BK == 32) ? 1 : 0;
    constexpr int KS = BK / 32;
    constexpr int NA = TM * BK / 2048;
    constexpr int NB = TN * BK / 2048;
    constexpr int NCT = (MODE == 0) ? 32 : (512 / TN);

    const int ct = wb % NCT;
    const int rowBase = (wb / NCT) * TM;

    const ushort* __restrict__ Bmat;
    int which = 0, matCol;
    if (MODE == 0) {
        which = ct / (512 / TN);
        matCol = (ct % (512 / TN)) * TN;
        Bmat = Bt + (size_t)which * 262144;
    } else {
        matCol = ct * TN;
        Bmat = Bt;
    }

    const int wave = tid >> 6, lane = tid & 63;
    const int q = lane >> 4, ln = lane & 15;
    const int mB = (wave >> 1) * WM, nB = (wave & 1) * WN;

    int fuA[NA], fuB[NB];
    const ushort* gA[NA];
    const ushort* gB[NB];
#pragma unroll
    for (int u = 0; u < NA; u++) {
        int fu = tid * 8 + u * 2048;
        int r = fu / BK;
        int slot = (fu >> 3) & (CH - 1);
        int gc = slot ^ ((r >> SH) & (CH - 1));
        fuA[u] = fu;
        gA[u] = A + (size_t)(rowBase + r) * 512 + gc * 8;
    }
#pragma unroll
    for (int u = 0; u < NB; u++) {
        int fu = tid * 8 + u * 2048;
        int r = fu / BK;
        int slot = (fu >> 3) & (CH - 1);
        int gc = slot ^ ((r >> SH) & (CH - 1));
        fuB[u] = fu;
        gB[u] = Bmat + (size_t)(matCol + r) * 512 + gc * 8;
    }

    f32x4 acc[FM][FN];
#pragma unroll
    for (int i = 0; i < FM; i++)
#pragma unroll
        for (int j = 0; j < FN; j++) acc[i][j] = (f32x4){0.f, 0.f, 0.f, 0.f};

    int aoff[FM][KS], boff[FN][KS];
#pragma unroll
    for (int i = 0; i < FM; i++) {
        int ra = mB + i * 16 + ln;
#pragma unroll
        for (int ks = 0; ks < KS; ks++)
            aoff[i][ks] = ra * BK
                + (((ks * 4 + q) ^ ((ra >> SH) & (CH - 1))) * 8);
    }
#pragma unroll
    for (int j = 0; j < FN; j++) {
        int rb = nB + j * 16 + ln;
#pragma unroll
        for (int ks = 0; ks < KS; ks++)
            boff[j][ks] = rb * BK
                + (((ks * 4 + q) ^ ((rb >> SH) & (CH - 1))) * 8);
    }

#pragma unroll
    for (int u = 0; u < NA; u++) async16(&AsB[fuA[u]], gA[u]);
#pragma unroll
    for (int u = 0; u < NB; u++) async16(&BsB[fuB[u]], gB[u]);

    int cur = 0;
    for (int kb = 0; kb < 512; kb += BK) {
        __syncthreads();
        if (kb + BK < 512) {
            int nxt = (cur ^ 1);
#pragma unroll
            for (int u = 0; u < NA; u++)
                async16(&AsB[nxt * TM * BK + fuA[u]], gA[u] + kb + BK);
#pragma unroll
            for (int u = 0; u < NB; u++)
                async16(&BsB[nxt * TN * BK + fuB[u]], gB[u] + kb + BK);
        }
#pragma unroll
        for (int ks = 0; ks < KS; ks++) {
            s16x8 af[FM], bf[FN];
#pragma unroll
            for (int i = 0; i < FM; i++)
                af[i] = *(const s16x8*)&AsB[cur * TM * BK + aoff[i][ks]];
#pragma unroll
            for (int j = 0; j < FN; j++)
                bf[j] = *(const s16x8*)&BsB[cur * TN * BK + boff[j][ks]];
#pragma unroll
            for (int i = 0; i < FM; i++)
#pragma unroll
                for (int j = 0; j < FN; j++)
                    acc[i][j] = __builtin_amdgcn_mfma_f32_16x16x32_bf16(
                        af[i], bf[j], acc[i][j], 0, 0, 0);
        }
        cur ^= 1;
    }

    // epilogue: C/D layout col=lane&15, row=quad*4+reg (m89-verified)
    if (MODE == 0) {
        ushort* __restrict__ Out = (which == 0) ? (ushort*)O0v
                                  : (which == 1) ? (ushort*)O1v
                                  : (which == 2) ? (ushort*)O2v : (ushort*)O3v;
#pragma unroll
        for (int i = 0; i < FM; i++)
#pragma unroll
            for (int j = 0; j < FN; j++) {
                int col = matCol + nB + j * 16 + ln;
#pragma unroll
                for (int r = 0; r < 4; r++) {
                    int row = rowBase + mB + i * 16 + q * 4 + r;
                    float v = acc[i][j][r];
                    if (which <= 1) v = fmaxf(v, 0.f);
                    else if (which == 3) v = 1.f / (1.f + expf(-(v + bg[col])));
                    Out[(size_t)row * 512 + col] = f2bf(v);
                }
            }
    } else {
        float* __restrict__ Out = (float*)O0v;
#pragma unroll
        for (int i = 0; i < FM; i++)
#pragma unroll
            for (int j = 0; j < FN; j++) {
                int col = matCol + nB + j * 16 + ln;
#pragma unroll
                for (int r = 0; r < 4; r++) {
                    int row = rowBase + mB + i * 16 + q * 4 + r;
                    Out[(size_t)row * 512 + col] = acc[i][j][r];
                }
            }
    }
}

// chunk KV sums via MFMA; stores ScT[e][d] transposed (round-5 design).
__device__ __forceinline__ void kv_body(
    int blk, int tid,
    const ushort* __restrict__ Kg, const ushort* __restrict__ Vg,
    ushort* __restrict__ Sst, float* __restrict__ Zst, SmemKV& sm)
{
    const int bh = blk >> 5, g = blk & 31;
    const int b = bh >> 3, h = bh & 7;
    const int rBase = b * T_ + g * C_;
    const int colB = h * DK_;

    {
        int row = tid >> 3, c8 = (tid & 7) * 8;
        float a = (float)(g * C_ + row) * PI_OVER_2T;
        float ca = cosf(a), sa = sinf(a);
        size_t ga = (size_t)(rBase + row) * D_ + colB + c8;
        uint4 kraw = *(const uint4*)&Kg[ga];
        uint4 vraw = *(const uint4*)&Vg[ga];
        const ushort* kp = (const ushort*)&kraw;
        const ushort* vp = (const ushort*)&vraw;
#pragma unroll
        for (int u = 0; u < 8; u++) {
            float kf = bf2f(kp[u]);
            sm.KcT[(c8 + u) * 40 + row] = f2bf(kf * ca);
            sm.KsT[(c8 + u) * 40 + row] = f2bf(kf * sa);
            sm.VT [(c8 + u) * 40 + row] = vp[u];
        }
    }
    __syncthreads();

    if (tid < 128) {
        int d = tid & 63;
        const ushort* src = (tid < 64) ? sm.KcT : sm.KsT;
        float zsum = 0.f;
#pragma unroll
        for (int t = 0; t < C_; t++) zsum += bf2f(src[d * 40 + t]);
        Zst[(size_t)blk * 128 + tid] = zsum;
    }

    const int wave = tid >> 6, lane = tid & 63;
    const int q = lane >> 4, ln = lane & 15;
    s16x8 av = *(const s16x8*)&sm.VT[(wave * 16 + ln) * 40 + q * 8];
    ushort* Sp = Sst + (size_t)blk * 8192;
#pragma unroll
    for (int nj = 0; nj < 4; nj++) {
        s16x8 bc = *(const s16x8*)&sm.KcT[(nj * 16 + ln) * 40 + q * 8];
        s16x8 bs = *(const s16x8*)&sm.KsT[(nj * 16 + ln) * 40 + q * 8];
        f32x4 ac = __builtin_amdgcn_mfma_f32_16x16x32_bf16(
            av, bc, (f32x4){0.f, 0.f, 0.f, 0.f}, 0, 0, 0);
        f32x4 as = __builtin_amdgcn_mfma_f32_16x16x32_bf16(
            av, bs, (f32x4){0.f, 0.f, 0.f, 0.f}, 0, 0, 0);
#pragma unroll
        for (int r = 0; r < 4; r++) {
            int e = wave * 16 + q * 4 + r;
            int d = nj * 16 + ln;
            Sp[e * 64 + d] = f2bf(ac[r]);
            Sp[4096 + e * 64 + d] = f2bf(as[r]);
        }
    }
}

// exclusive chunk scan, latency-pipelined (32 independent loads in flight)
__device__ __forceinline__ void scan_body(
    int id, ushort* __restrict__ Sst, float* __restrict__ Zst)
{
    if (id < 32768) {
        int bh = id >> 11, i4 = (id & 2047) * 4;
        size_t base = (size_t)bh * (G_ * 8192) + i4;
        ushort4 v[G_];
#pragma unroll
        for (int g = 0; g < G_; g++)
            v[g] = *(const ushort4*)&Sst[base + (size_t)g * 8192];
        float rx = 0.f, ry = 0.f, rz = 0.f, rw = 0.f;
#pragma unroll
        for (int g = 0; g < G_; g++) {
            ushort4 t = v[g];
            ushort4 o;
            o.x = f2bf(rx); o.y = f2bf(ry); o.z = f2bf(rz); o.w = f2bf(rw);
            *(ushort4*)&Sst[base + (size_t)g * 8192] = o;
            rx += bf2f(t.x); ry += bf2f(t.y);
            rz += bf2f(t.z); rw += bf2f(t.w);
        }
    } else {
        int id2 = id - 32768;
        if (id2 >= 512) return;
        int bh = id2 >> 5, i4 = (id2 & 31) * 4;
        size_t base = (size_t)bh * (G_ * 128) + i4;
        float4 v[G_];
#pragma unroll
        for (int g = 0; g < G_; g++)
            v[g] = *(const float4*)&Zst[base + (size_t)g * 128];
        float4 run = make_float4(0.f, 0.f, 0.f, 0.f);
#pragma unroll
        for (int g = 0; g < G_; g++) {
            float4 t = v[g];
            *(float4*)&Zst[base + (size_t)g * 128] = run;
            run.x += t.x; run.y += t.y; run.z += t.z; run.w += t.w;
        }
    }
}

// per-chunk output via MFMA (round-5 design)
__device__ __forceinline__ void oc_body(
    int blk, int tid,
    const ushort* __restrict__ Qg, const ushort* __restrict__ Kg,
    const ushort* __restrict__ Vg, const ushort* __restrict__ Gg,
    const ushort* __restrict__ Sst, const float* __restrict__ Zst,
    ushort* __restrict__ Op, SmemOC& sm)
{
    const int bh = blk >> 5, g = blk & 31;
    const int b = bh >> 3, h = bh & 7;
    const int rBase = b * T_ + g * C_;
    const int colB = h * DK_;
    const int wave = tid >> 6, lane = tid & 63;
    const int q = lane >> 4, ln = lane & 15;

    {
        int row = tid >> 3, c8 = (tid & 7) * 8;
        uint4 vraw = *(const uint4*)&Vg[(size_t)(rBase + row) * D_ + colB + c8];
        const ushort* vp = (const ushort*)&vraw;
#pragma unroll
        for (int u = 0; u < 8; u++) sm.VT[(c8 + u) * 40 + row] = vp[u];
    }

    const int mi = wave >> 1, njp = wave & 1;
    const ushort* qrow = Qg + (size_t)(rBase + mi * 16 + ln) * D_ + colB;
    s16x8 aq0 = *(const s16x8*)&qrow[q * 8];
    s16x8 aq1 = *(const s16x8*)&qrow[32 + q * 8];
    {
        const ushort* krow = Kg + (size_t)(rBase + njp * 16 + ln) * D_ + colB;
        s16x8 bk0 = *(const s16x8*)&krow[q * 8];
        s16x8 bk1 = *(const s16x8*)&krow[32 + q * 8];
        f32x4 pacc = __builtin_amdgcn_mfma_f32_16x16x32_bf16(
            aq0, bk0, (f32x4){0.f, 0.f, 0.f, 0.f}, 0, 0, 0);
        pacc = __builtin_amdgcn_mfma_f32_16x16x32_bf16(aq1, bk1, pacc, 0, 0, 0);
        int sl = njp * 16 + ln;
        float as_ = (float)(g * C_ + sl) * PI_OVER_2T;
        float cs_ = cosf(as_), ss_ = sinf(as_);
#pragma unroll
        for (int r = 0; r < 4; r++) {
            int tl = mi * 16 + q * 4 + r;
            float at = (float)(g * C_ + tl) * PI_OVER_2T;
            float w = (sl <= tl) ? (cosf(at) * cs_ + sinf(at) * ss_) : 0.f;
            sm.Pb[tl * 40 + sl] = f2bf(pacc[r] * w);
        }
    }
    __syncthreads();

    {
        int t = tid >> 3, sub = tid & 7;
        uint4 qraw = *(const uint4*)&Qg[(size_t)(rBase + t) * D_ + colB + sub * 8];
        const ushort* qp = (const ushort*)&qraw;
        const float* zcp = Zst + (size_t)blk * 128 + sub * 8;
        float4 zc0 = *(const float4*)&zcp[0];
        float4 zc1 = *(const float4*)&zcp[4];
        float4 zs0 = *(const float4*)&zcp[64];
        float4 zs1 = *(const float4*)&zcp[68];
        float pc = 0.f, ps = 0.f;
        float zcv[8] = {zc0.x, zc0.y, zc0.z, zc0.w, zc1.x, zc1.y, zc1.z, zc1.w};
        float zsv[8] = {zs0.x, zs0.y, zs0.z, zs0.w, zs1.x, zs1.y, zs1.z, zs1.w};
#pragma unroll
        for (int u = 0; u < 8; u++) {
            float qf = bf2f(qp[u]);
            pc += qf * zcv[u]; ps += qf * zsv[u];
        }
        float pr = 0.f;
#pragma unroll
        for (int u = 0; u < 4; u++) pr += bf2f(sm.Pb[t * 40 + sub * 4 + u]);
#pragma unroll
        for (int m = 1; m < 8; m <<= 1) {
            pc += __shfl_xor(pc, m);
            ps += __shfl_xor(ps, m);
            pr += __shfl_xor(pr, m);
        }
        if (sub == 0) {
            float at = (float)(g * C_ + t) * PI_OVER_2T;
            float z = cosf(at) * pc + sinf(at) * ps + pr;
            sm.zinv[t] = 1.f / fmaxf(z, 1e-6f);
        }
    }
    __syncthreads();

    {
        float am = (float)(g * C_ + mi * 16 + ln) * PI_OVER_2T;
        float cm = cosf(am), sm_ = sinf(am);
        s16x8 aqc0 = bscale(aq0, cm), aqc1 = bscale(aq1, cm);
        s16x8 aqs0 = bscale(aq0, sm_), aqs1 = bscale(aq1, sm_);
        s16x8 pf = *(const s16x8*)&sm.Pb[(mi * 16 + ln) * 40 + q * 8];
        const ushort* Sp = Sst + (size_t)blk * 8192;
#pragma unroll
        for (int jj = 0; jj < 2; jj++) {
            int nj = 2 * (wave & 1) + jj;
            const ushort* scp = Sp + (nj * 16 + ln) * 64;
            s16x8 bc0 = *(const s16x8*)&scp[q * 8];
            s16x8 bc1 = *(const s16x8*)&scp[32 + q * 8];
            s16x8 bs0 = *(const s16x8*)&scp[4096 + q * 8];
            s16x8 bs1 = *(const s16x8*)&scp[4096 + 32 + q * 8];
            s16x8 bv  = *(const s16x8*)&sm.VT[(nj * 16 + ln) * 40 + q * 8];
            f32x4 acc = __builtin_amdgcn_mfma_f32_16x16x32_bf16(
                pf, bv, (f32x4){0.f, 0.f, 0.f, 0.f}, 0, 0, 0);
            acc = __builtin_amdgcn_mfma_f32_16x16x32_bf16(aqc0, bc0, acc, 0, 0, 0);
            acc = __builtin_amdgcn_mfma_f32_16x16x32_bf16(aqc1, bc1, acc, 0, 0, 0);
            acc = __builtin_amdgcn_mfma_f32_16x16x32_bf16(aqs0, bs0, acc, 0, 0, 0);
            acc = __builtin_amdgcn_mfma_f32_16x16x32_bf16(aqs1, bs1, acc, 0, 0, 0);
#pragma unroll
            for (int r = 0; r < 4; r++) {
                int tl = mi * 16 + q * 4 + r;
                int e = nj * 16 + ln;
                size_t go = (size_t)(rBase + tl) * D_ + colB + e;
                float o = acc[r] * sm.zinv[tl] * bf2f(Gg[go]);
                Op[go] = f2bf(o);
            }
        }
    }
}

// ---------------------------------------------------------------------------
// MEGA cooperative kernel: all 6 phases, grid 512 x 256, 2 blocks/CU.
// __threadfence() both sides of grid.sync(): release writeback + acquire
// invalidate (per-XCD L2 non-coherence, G16).
// ---------------------------------------------------------------------------
__global__ __launch_bounds__(256, 2) void k_mega(
    const float* __restrict__ x,
    const float* __restrict__ Wq, const float* __restrict__ Wk,
    const float* __restrict__ Wv, const float* __restrict__ Wg,
    const float* __restrict__ Wo, const float* __restrict__ bg,
    float* __restrict__ out,
    ushort* __restrict__ xb, ushort* __restrict__ WtAll,
    ushort* __restrict__ Qg, ushort* __restrict__ Kg,
    ushort* __restrict__ Vg, ushort* __restrict__ Gg,
    ushort* __restrict__ Sst, ushort* __restrict__ Opb,
    float* __restrict__ Zst)
{
    __shared__ SmemU sm;
    const int wb = blockIdx.x, tid = threadIdx.x;
    cg::grid_group grid = cg::this_grid();

    // phase 0: convert x + 5 weights (1344 units, grid-stride)
    for (int u = wb; u < 1344; u += 512)
        conv_body(u, tid, x, Wq, Wk, Wv, Wg, Wo, xb, WtAll, sm.cv);
    __threadfence(); grid.sync(); __threadfence();

    // phase 1: QKVG projection GEMM (512 blocks = 32 ct x 16 row-tiles)
    gemm_body<0, 128, 64, 64>(wb, tid, xb, WtAll, bg, Qg, Kg, Vg, Gg,
                              sm.g0.As, sm.g0.Bs);
    __threadfence(); grid.sync(); __threadfence();

    // phase 2: per-chunk KV outer-product sums
    kv_body(wb, tid, Kg, Vg, Sst, Zst, sm.kv);
    __threadfence(); grid.sync(); __threadfence();

    // phase 3: exclusive chunk scan
    scan_body(wb * 256 + tid, Sst, Zst);
    __threadfence(); grid.sync(); __threadfence();

    // phase 4: per-chunk output
    oc_body(wb, tid, Qg, Kg, Vg, Gg, Sst, Zst, Opb, sm.oc);
    __threadfence(); grid.sync(); __threadfence();

    // phase 5: output projection (512 blocks = 16 ct x 32 row-tiles)
    gemm_body<1, 64, 32, 64>(wb, tid, Opb, WtAll + (size_t)4 * 262144, nullptr,
                             out, nullptr, nullptr, nullptr,
                             sm.g1.As, sm.g1.Bs);
}

// ---------------------------------------------------------------------------
// Standalone fallback kernels (used if cooperative launch fails)
// ---------------------------------------------------------------------------
__global__ __launch_bounds__(256) void k_conv(
    const float* __restrict__ x,
    const float* __restrict__ Wq, const float* __restrict__ Wk,
    const float* __restrict__ Wv, const float* __restrict__ Wg,
    const float* __restrict__ Wo,
    ushort* __restrict__ xb, ushort* __restrict__ WtAll)
{
    __shared__ SmemCv sm;
    conv_body(blockIdx.x, threadIdx.x, x, Wq, Wk, Wv, Wg, Wo, xb, WtAll, sm);
}

template<int MODE, int TM, int TN, int BK>
__global__ __launch_bounds__(256) void k_gemm(
    const ushort* __restrict__ A, const ushort* __restrict__ Bt,
    const float* __restrict__ bg,
    void* __restrict__ O0v, void* __restrict__ O1v,
    void* __restrict__ O2v, void* __restrict__ O3v)
{
    __shared__ ushort As[2 * TM * BK];
    __shared__ ushort Bs[2 * TN * BK];
    constexpr int NCT = (MODE == 0) ? 32 : (512 / TN);
    int wb = blockIdx.y * NCT + blockIdx.x;
    gemm_body<MODE, TM, TN, BK>(wb, threadIdx.x, A, Bt, bg,
                                O0v, O1v, O2v, O3v, As, Bs);
}

__global__ __launch_bounds__(256) void k_chunk_kv(
    const ushort* __restrict__ Kg, const ushort* __restrict__ Vg,
    ushort* __restrict__ Sst, float* __restrict__ Zst)
{
    __shared__ SmemKV sm;
    kv_body(blockIdx.x, threadIdx.x, Kg, Vg, Sst, Zst, sm);
}

__global__ __launch_bounds__(256) void k_scan(
    ushort* __restrict__ Sst, float* __restrict__ Zst)
{
    scan_body(blockIdx.x * 256 + threadIdx.x, Sst, Zst);
}

__global__ __launch_bounds__(256) void k_out_chunk(
    const ushort* __restrict__ Qg, const ushort* __restrict__ Kg,
    const ushort* __restrict__ Vg, const ushort* __restrict__ Gg,
    const ushort* __restrict__ Sst, const float* __restrict__ Zst,
    ushort* __restrict__ Op)
{
    __shared__ SmemOC sm;
    oc_body(blockIdx.x, threadIdx.x, Qg, Kg, Vg, Gg, Sst, Zst, Op, sm);
}

// ---------------------------------------------------------------------------
extern "C" void kernel_launch(void* const* d_in, const int* in_sizes, int n_in,
                              void* d_out, int out_size, void* d_ws, size_t ws_size,
                              hipStream_t stream)
{
    const float* x  = (const float*)d_in[0];
    const float* Wq = (const float*)d_in[1];
    const float* Wk = (const float*)d_in[2];
    const float* Wv = (const float*)d_in[3];
    const float* Wo = (const float*)d_in[4];
    const float* Wg = (const float*)d_in[5];
    const float* bg = (const float*)d_in[6];
    float* out = (float*)d_out;

    ushort* wsu = (ushort*)d_ws;
    ushort* xb    = wsu;                   // 1M bf16
    ushort* WtAll = xb + 1048576;          // 5*256K bf16
    ushort* Qg    = WtAll + 1310720;       // 1M bf16 each
    ushort* Kg    = Qg + 1048576;
    ushort* Vg    = Kg + 1048576;
    ushort* Gg    = Vg + 1048576;
    ushort* Sst   = Gg + 1048576;          // 4M bf16 (ScT/SsT per chunk)
    ushort* Opb   = Sst + 4194304;         // 1M bf16
    float*  Zst   = (float*)(Opb + 1048576);  // 64K f32

    void* args[] = { (void*)&x, (void*)&Wq, (void*)&Wk, (void*)&Wv,
                     (void*)&Wg, (void*)&Wo, (void*)&bg, (void*)&out,
                     (void*)&xb, (void*)&WtAll, (void*)&Qg, (void*)&Kg,
                     (void*)&Vg, (void*)&Gg, (void*)&Sst, (void*)&Opb,
                     (void*)&Zst };
    hipError_t err = hipLaunchCooperativeKernel(
        (const void*)k_mega, dim3(512), dim3(256), args, 0, stream);

    if (err != hipSuccess) {
        (void)hipGetLastError();  // clear sticky error; fall back
        dim3 blk(256);
        k_conv<<<dim3(1344), blk, 0, stream>>>(x, Wq, Wk, Wv, Wg, Wo, xb, WtAll);
        k_gemm<0, 128, 64, 64><<<dim3(32, 16), blk, 0, stream>>>(
            xb, WtAll, bg, Qg, Kg, Vg, Gg);
        k_chunk_kv<<<dim3(NBH_ * G_), blk, 0, stream>>>(Kg, Vg, Sst, Zst);
        k_scan<<<dim3(130), blk, 0, stream>>>(Sst, Zst);
        k_out_chunk<<<dim3(NBH_ * G_), blk, 0, stream>>>(
            Qg, Kg, Vg, Gg, Sst, Zst, Opb);
        k_gemm<1, 64, 32, 64><<<dim3(16, 32), blk, 0, stream>>>(
            Opb, WtAll + (size_t)4 * 262144, nullptr,
            out, nullptr, nullptr, nullptr);
    }
}

// Round 8
// 104.858 us; speedup vs baseline: 7.8968x; 7.8968x over previous
//
#include <hip/hip_runtime.h>
#include <math.h>

// Problem constants
#define B_ 2
#define T_ 1024
#define D_ 512
#define H_ 8
#define DK_ 64
#define NBH_ 16          // B*H
#define C_ 32            // chunk length
#define G_ 32            // T/C chunks

#define PI_OVER_2T 0.00153398078788564122971808758949f  /* pi/2048 */

typedef float f32x4 __attribute__((ext_vector_type(4)));
typedef short s16x8 __attribute__((ext_vector_type(8)));

__device__ __forceinline__ ushort f2bf(float x) {
    unsigned u = __float_as_uint(x);
    unsigned r = (u + 0x7fffu + ((u >> 16) & 1u)) >> 16;   // RNE
    return (ushort)r;
}
__device__ __forceinline__ float bf2f(ushort u) {
    return __uint_as_float((unsigned)u << 16);
}
__device__ __forceinline__ s16x8 bscale(s16x8 v, float s) {
    s16x8 r;
#pragma unroll
    for (int u = 0; u < 8; u++)
        r[u] = (short)f2bf(bf2f((ushort)v[u]) * s);
    return r;
}

// async global->LDS, 16B/lane; LDS dest must be tid-contiguous (m104).
__device__ __forceinline__ void async16(void* lds, const void* g) {
    __builtin_amdgcn_global_load_lds(
        (const __attribute__((address_space(1))) void*)g,
        (__attribute__((address_space(3))) void*)lds, 16, 0, 0);
}

// ---------------------------------------------------------------------------
// Fused convert kernel (round-6 verbatim).
// blocks 0..1023: x -> xb bf16.  1024..1343: 5 weights -> WtAll bf16 (n,k).
// ---------------------------------------------------------------------------
__global__ __launch_bounds__(256) void k_conv(
    const float* __restrict__ x,
    const float* __restrict__ Wq, const float* __restrict__ Wk,
    const float* __restrict__ Wv, const float* __restrict__ Wg,
    const float* __restrict__ Wo,
    ushort* __restrict__ xb, ushort* __restrict__ WtAll)
{
    __shared__ float Ts[64][65];
    const int bx = blockIdx.x;
    const int tid = threadIdx.x;
    if (bx < 1024) {
        int i = (bx * 256 + tid) * 4;
        float4 v = *(const float4*)&x[i];
        ushort4 o;
        o.x = f2bf(v.x); o.y = f2bf(v.y); o.z = f2bf(v.z); o.w = f2bf(v.w);
        *(ushort4*)&xb[i] = o;
        return;
    }
    const int bid = bx - 1024;
    const int mi = bid >> 6;
    const int t64 = bid & 63;
    const float* __restrict__ W = (mi == 0) ? Wq : (mi == 1) ? Wk
                                 : (mi == 2) ? Wv : (mi == 3) ? Wg : Wo;
    const int tr = t64 >> 3, tc = t64 & 7;
#pragma unroll
    for (int p = 0; p < 4; p++) {
        int row = p * 16 + (tid >> 4);
        int c4 = (tid & 15) * 4;
        float4 v = *(const float4*)&W[(size_t)(tr * 64 + row) * 512 + tc * 64 + c4];
        Ts[row][c4 + 0] = v.x; Ts[row][c4 + 1] = v.y;
        Ts[row][c4 + 2] = v.z; Ts[row][c4 + 3] = v.w;
    }
    __syncthreads();
    const int nl = tid >> 2, kc = (tid & 3) * 16;
    ushort buf[16];
#pragma unroll
    for (int u = 0; u < 16; u++) buf[u] = f2bf(Ts[kc + u][nl]);
    ushort* dst = WtAll + (size_t)mi * 262144 + (size_t)(tc * 64 + nl) * 512
                  + tr * 64 + kc;
    *(uint4*)dst = *(uint4*)&buf[0];
    *(uint4*)(dst + 8) = *(uint4*)&buf[8];
}

// ---------------------------------------------------------------------------
// FUSED dual-matrix projection GEMM + per-chunk KV state epilogue.
// Grid (16, 32): ct 0..7 -> Q+G col-tile ct; ct 8..15 -> K+V head ct-8.
// TM=64 (rows = 2 chunks of one head for KV), TN=64 per matrix, BK=64.
// 4 waves in 2x2: wave covers 32 rows x 32 cols per matrix (FM=2, FN=2).
// KV epilogue: write Kg/Vg, in-register z (exact f32, shuffle over quads),
// transpose Kc/Ks/V to LDS [d][t] (pad 72: 144B rows, 16B-aligned, 2-way
// banks = free), then 16 state-MFMAs/wave -> ScT/SsT local sums + Zst.
// Replaces the separate k_chunk_kv dispatch.
// ---------------------------------------------------------------------------
__global__ __launch_bounds__(256) void k_g0(
    const ushort* __restrict__ A, const ushort* __restrict__ WtAll,
    const float* __restrict__ bg,
    ushort* __restrict__ Qg, ushort* __restrict__ Kg,
    ushort* __restrict__ Vg, ushort* __restrict__ Gg,
    ushort* __restrict__ Sst, float* __restrict__ Zst)
{
    __shared__ union {
        struct { ushort As[2][64 * 64]; ushort Bs[2][2 * 64 * 64]; } s; // 48 KB
        struct { ushort KcT[64 * 72]; ushort KsT[64 * 72];
                 ushort VT[64 * 72]; } e;                               // 27 KB
    } sm;

    const int tid = threadIdx.x;
    const int ct = blockIdx.x;
    const int rowBase = blockIdx.y * 64;
    const bool isKV = (ct >= 8);
    const int matCol = (ct & 7) * 64;
    const ushort* __restrict__ B0 = WtAll + (size_t)(isKV ? 1 : 0) * 262144;
    const ushort* __restrict__ B1 = WtAll + (size_t)(isKV ? 2 : 3) * 262144;

    const int wave = tid >> 6, lane = tid & 63;
    const int q = lane >> 4, ln = lane & 15;
    const int mB = (wave >> 1) * 32, nB = (wave & 1) * 32;

    // staging: 2 A-issues + 2 B-issues per matrix per thread per tile
    int fu[2];
    const ushort* gA[2];
    const ushort* gB0[2];
    const ushort* gB1[2];
#pragma unroll
    for (int u = 0; u < 2; u++) {
        int f = tid * 8 + u * 2048;
        int r = f >> 6;                       // row 0..63
        int gc = ((f >> 3) & 7) ^ (r & 7);    // XOR chunk swizzle
        fu[u] = f;
        gA[u]  = A  + (size_t)(rowBase + r) * 512 + gc * 8;
        gB0[u] = B0 + (size_t)(matCol + r) * 512 + gc * 8;
        gB1[u] = B1 + (size_t)(matCol + r) * 512 + gc * 8;
    }

    f32x4 accA[2][2], accB[2][2];
#pragma unroll
    for (int i = 0; i < 2; i++)
#pragma unroll
        for (int j = 0; j < 2; j++) {
            accA[i][j] = (f32x4){0.f, 0.f, 0.f, 0.f};
            accB[i][j] = (f32x4){0.f, 0.f, 0.f, 0.f};
        }

    int aoff[2][2], boff[2][2];
#pragma unroll
    for (int i = 0; i < 2; i++) {
        int ra = mB + i * 16 + ln;
#pragma unroll
        for (int ks = 0; ks < 2; ks++)
            aoff[i][ks] = ra * 64 + (((ks * 4 + q) ^ (ra & 7)) * 8);
    }
#pragma unroll
    for (int j = 0; j < 2; j++) {
        int rb = nB + j * 16 + ln;
#pragma unroll
        for (int ks = 0; ks < 2; ks++)
            boff[j][ks] = rb * 64 + (((ks * 4 + q) ^ (rb & 7)) * 8);
    }

    // prologue prefetch into buf 0
#pragma unroll
    for (int u = 0; u < 2; u++) {
        async16(&sm.s.As[0][fu[u]], gA[u]);
        async16(&sm.s.Bs[0][fu[u]], gB0[u]);
        async16(&sm.s.Bs[0][4096 + fu[u]], gB1[u]);
    }

    int cur = 0;
    for (int kb = 0; kb < 512; kb += 64) {
        __syncthreads();
        if (kb + 64 < 512) {
            int nxt = cur ^ 1;
#pragma unroll
            for (int u = 0; u < 2; u++) {
                async16(&sm.s.As[nxt][fu[u]], gA[u] + kb + 64);
                async16(&sm.s.Bs[nxt][fu[u]], gB0[u] + kb + 64);
                async16(&sm.s.Bs[nxt][4096 + fu[u]], gB1[u] + kb + 64);
            }
        }
#pragma unroll
        for (int ks = 0; ks < 2; ks++) {
            s16x8 af[2], b0f[2], b1f[2];
#pragma unroll
            for (int i = 0; i < 2; i++)
                af[i] = *(const s16x8*)&sm.s.As[cur][aoff[i][ks]];
#pragma unroll
            for (int j = 0; j < 2; j++) {
                b0f[j] = *(const s16x8*)&sm.s.Bs[cur][boff[j][ks]];
                b1f[j] = *(const s16x8*)&sm.s.Bs[cur][4096 + boff[j][ks]];
            }
#pragma unroll
            for (int i = 0; i < 2; i++)
#pragma unroll
                for (int j = 0; j < 2; j++) {
                    accA[i][j] = __builtin_amdgcn_mfma_f32_16x16x32_bf16(
                        af[i], b0f[j], accA[i][j], 0, 0, 0);
                    accB[i][j] = __builtin_amdgcn_mfma_f32_16x16x32_bf16(
                        af[i], b1f[j], accB[i][j], 0, 0, 0);
                }
        }
        cur ^= 1;
    }
    __syncthreads();   // all waves done with As/Bs before union reuse

    // epilogue. C/D layout: col=lane&15, row=quad*4+reg (m89-verified).
    if (!isKV) {
        // Q (relu) and G (sigmoid + bias)
#pragma unroll
        for (int i = 0; i < 2; i++)
#pragma unroll
            for (int j = 0; j < 2; j++) {
                int col = matCol + nB + j * 16 + ln;
#pragma unroll
                for (int r = 0; r < 4; r++) {
                    int row = rowBase + mB + i * 16 + q * 4 + r;
                    Qg[(size_t)row * 512 + col] = f2bf(fmaxf(accA[i][j][r], 0.f));
                    Gg[(size_t)row * 512 + col] =
                        f2bf(1.f / (1.f + expf(-(accB[i][j][r] + bg[col]))));
                }
            }
        return;
    }

    // ---- KV epilogue ----
    const int h = ct - 8;
    const int b = rowBase >> 10;
    const int c = wave >> 1;                           // chunk of this wave
    const int gG = ((rowBase & 1023) >> 5) + c;        // global chunk index
    const int blk = (b * 8 + h) * 32 + gG;

    // pass 1: global K/V writes, LDS transpose, in-register z partials
    float zc[2] = {0.f, 0.f}, zs[2] = {0.f, 0.f};
#pragma unroll
    for (int i = 0; i < 2; i++)
#pragma unroll
        for (int r = 0; r < 4; r++) {
            int tLoc = mB + i * 16 + q * 4 + r;        // 0..63 local row
            int rowG = rowBase + tLoc;
            float a = (float)(rowG & 1023) * PI_OVER_2T;
            float ca = cosf(a), sa = sinf(a);
#pragma unroll
            for (int j = 0; j < 2; j++) {
                int col = nB + j * 16 + ln;            // 0..63 (d / e)
                float kv = fmaxf(accA[i][j][r], 0.f);
                float vv = accB[i][j][r];
                size_t go = (size_t)rowG * 512 + h * 64 + col;
                Kg[go] = f2bf(kv);
                Vg[go] = f2bf(vv);
                float kc = kv * ca, ks = kv * sa;
                sm.e.KcT[col * 72 + tLoc] = f2bf(kc);
                sm.e.KsT[col * 72 + tLoc] = f2bf(ks);
                sm.e.VT [col * 72 + tLoc] = f2bf(vv);
                zc[j] += kc; zs[j] += ks;
            }
        }
    // reduce z over quads (rows of the chunk are split across q only)
#pragma unroll
    for (int j = 0; j < 2; j++) {
        zc[j] += __shfl_xor(zc[j], 16); zc[j] += __shfl_xor(zc[j], 32);
        zs[j] += __shfl_xor(zs[j], 16); zs[j] += __shfl_xor(zs[j], 32);
    }
    if (q == 0) {
#pragma unroll
        for (int j = 0; j < 2; j++) {
            int d = nB + j * 16 + ln;
            Zst[(size_t)blk * 128 + d] = zc[j];
            Zst[(size_t)blk * 128 + 64 + d] = zs[j];
        }
    }
    __syncthreads();

    // pass 2: state MFMAs. wave -> chunk c = wave>>1, e-half = wave&1.
    // ScT[e][d] = sum_t V[t][e]*Kc[t][d]; A=V^T, B=Kc^T; K=32 (one MFMA).
    {
        const int eh = (wave & 1) * 32;
        ushort* Sp = Sst + (size_t)blk * 8192;
        s16x8 av[2];
#pragma unroll
        for (int fi = 0; fi < 2; fi++)
            av[fi] = *(const s16x8*)&sm.e.VT[(eh + fi * 16 + ln) * 72
                                            + c * 32 + q * 8];
#pragma unroll
        for (int fj = 0; fj < 4; fj++) {
            s16x8 bc = *(const s16x8*)&sm.e.KcT[(fj * 16 + ln) * 72
                                                + c * 32 + q * 8];
            s16x8 bs = *(const s16x8*)&sm.e.KsT[(fj * 16 + ln) * 72
                                                + c * 32 + q * 8];
#pragma unroll
            for (int fi = 0; fi < 2; fi++) {
                f32x4 sc = __builtin_amdgcn_mfma_f32_16x16x32_bf16(
                    av[fi], bc, (f32x4){0.f, 0.f, 0.f, 0.f}, 0, 0, 0);
                f32x4 ss = __builtin_amdgcn_mfma_f32_16x16x32_bf16(
                    av[fi], bs, (f32x4){0.f, 0.f, 0.f, 0.f}, 0, 0, 0);
#pragma unroll
                for (int rr = 0; rr < 4; rr++) {
                    int e = eh + fi * 16 + q * 4 + rr;
                    int d = fj * 16 + ln;
                    Sp[e * 64 + d] = f2bf(sc[rr]);
                    Sp[4096 + e * 64 + d] = f2bf(ss[rr]);
                }
            }
        }
    }
}

// ---------------------------------------------------------------------------
// Out-projection GEMM (round-6 template, MODE 1 only).
// ---------------------------------------------------------------------------
template<int MODE, int TM, int TN, int BK>
__global__ __launch_bounds__(256) void k_gemm(
    const ushort* __restrict__ A, const ushort* __restrict__ Bt,
    const float* __restrict__ bg,
    void* __restrict__ O0v, void* __restrict__ O1v,
    void* __restrict__ O2v, void* __restrict__ O3v)
{
    constexpr int WM = TM / 2, WN = TN / 2;
    constexpr int FM = WM / 16, FN = WN / 16;
    constexpr int CH = BK / 8;
    constexpr int SH = (BK == 32) ? 1 : 0;
    constexpr int KS = BK / 32;
    constexpr int NA = TM * BK / 2048;
    constexpr int NB = TN * BK / 2048;

    __shared__ ushort As[2][TM * BK];
    __shared__ ushort Bs[2][TN * BK];

    const int tid = threadIdx.x;
    const int ct = blockIdx.x;
    const int rowBase = blockIdx.y * TM;

    const int matCol = ct * TN;
    const ushort* __restrict__ Bmat = Bt;

    const int wave = tid >> 6, lane = tid & 63;
    const int q = lane >> 4, ln = lane & 15;
    const int mB = (wave >> 1) * WM, nB = (wave & 1) * WN;

    int fuA[NA], fuB[NB];
    const ushort* gA[NA];
    const ushort* gB[NB];
#pragma unroll
    for (int u = 0; u < NA; u++) {
        int fu = tid * 8 + u * 2048;
        int r = fu / BK;
        int slot = (fu >> 3) & (CH - 1);
        int gc = slot ^ ((r >> SH) & (CH - 1));
        fuA[u] = fu;
        gA[u] = A + (size_t)(rowBase + r) * 512 + gc * 8;
    }
#pragma unroll
    for (int u = 0; u < NB; u++) {
        int fu = tid * 8 + u * 2048;
        int r = fu / BK;
        int slot = (fu >> 3) & (CH - 1);
        int gc = slot ^ ((r >> SH) & (CH - 1));
        fuB[u] = fu;
        gB[u] = Bmat + (size_t)(matCol + r) * 512 + gc * 8;
    }

    f32x4 acc[FM][FN];
#pragma unroll
    for (int i = 0; i < FM; i++)
#pragma unroll
        for (int j = 0; j < FN; j++) acc[i][j] = (f32x4){0.f, 0.f, 0.f, 0.f};

    int aoff[FM][KS], boff[FN][KS];
#pragma unroll
    for (int i = 0; i < FM; i++) {
        int ra = mB + i * 16 + ln;
#pragma unroll
        for (int ks = 0; ks < KS; ks++)
            aoff[i][ks] = ra * BK + (((ks * 4 + q) ^ ((ra >> SH) & (CH - 1))) * 8);
    }
#pragma unroll
    for (int j = 0; j < FN; j++) {
        int rb = nB + j * 16 + ln;
#pragma unroll
        for (int ks = 0; ks < KS; ks++)
            boff[j][ks] = rb * BK + (((ks * 4 + q) ^ ((rb >> SH) & (CH - 1))) * 8);
    }

#pragma unroll
    for (int u = 0; u < NA; u++) async16(&As[0][fuA[u]], gA[u]);
#pragma unroll
    for (int u = 0; u < NB; u++) async16(&Bs[0][fuB[u]], gB[u]);

    int cur = 0;
    for (int kb = 0; kb < 512; kb += BK) {
        __syncthreads();
        if (kb + BK < 512) {
#pragma unroll
            for (int u = 0; u < NA; u++)
                async16(&As[cur ^ 1][fuA[u]], gA[u] + kb + BK);
#pragma unroll
            for (int u = 0; u < NB; u++)
                async16(&Bs[cur ^ 1][fuB[u]], gB[u] + kb + BK);
        }
#pragma unroll
        for (int ks = 0; ks < KS; ks++) {
            s16x8 af[FM], bf[FN];
#pragma unroll
            for (int i = 0; i < FM; i++)
                af[i] = *(const s16x8*)&As[cur][aoff[i][ks]];
#pragma unroll
            for (int j = 0; j < FN; j++)
                bf[j] = *(const s16x8*)&Bs[cur][boff[j][ks]];
#pragma unroll
            for (int i = 0; i < FM; i++)
#pragma unroll
                for (int j = 0; j < FN; j++)
                    acc[i][j] = __builtin_amdgcn_mfma_f32_16x16x32_bf16(
                        af[i], bf[j], acc[i][j], 0, 0, 0);
        }
        cur ^= 1;
    }

    float* __restrict__ Out = (float*)O0v;
#pragma unroll
    for (int i = 0; i < FM; i++)
#pragma unroll
        for (int j = 0; j < FN; j++) {
            int col = matCol + nB + j * 16 + ln;
#pragma unroll
            for (int r = 0; r < 4; r++) {
                int row = rowBase + mB + i * 16 + q * 4 + r;
                Out[(size_t)row * 512 + col] = acc[i][j][r];
            }
        }
}

// ---------------------------------------------------------------------------
// Exclusive chunk-scan, latency-pipelined (round-6 verbatim).
// ---------------------------------------------------------------------------
__global__ __launch_bounds__(256) void k_scan(
    ushort* __restrict__ Sst, float* __restrict__ Zst)
{
    int id = blockIdx.x * 256 + threadIdx.x;
    if (id < 32768) {
        int bh = id >> 11, i4 = (id & 2047) * 4;
        size_t base = (size_t)bh * (G_ * 8192) + i4;
        ushort4 v[G_];
#pragma unroll
        for (int g = 0; g < G_; g++)
            v[g] = *(const ushort4*)&Sst[base + (size_t)g * 8192];
        float rx = 0.f, ry = 0.f, rz = 0.f, rw = 0.f;
#pragma unroll
        for (int g = 0; g < G_; g++) {
            ushort4 t = v[g];
            ushort4 o;
            o.x = f2bf(rx); o.y = f2bf(ry); o.z = f2bf(rz); o.w = f2bf(rw);
            *(ushort4*)&Sst[base + (size_t)g * 8192] = o;
            rx += bf2f(t.x); ry += bf2f(t.y);
            rz += bf2f(t.z); rw += bf2f(t.w);
        }
    } else {
        int id2 = id - 32768;
        if (id2 >= 512) return;
        int bh = id2 >> 5, i4 = (id2 & 31) * 4;
        size_t base = (size_t)bh * (G_ * 128) + i4;
        float4 v[G_];
#pragma unroll
        for (int g = 0; g < G_; g++)
            v[g] = *(const float4*)&Zst[base + (size_t)g * 128];
        float4 run = make_float4(0.f, 0.f, 0.f, 0.f);
#pragma unroll
        for (int g = 0; g < G_; g++) {
            float4 t = v[g];
            *(float4*)&Zst[base + (size_t)g * 128] = run;
            run.x += t.x; run.y += t.y; run.z += t.z; run.w += t.w;
        }
    }
}

// ---------------------------------------------------------------------------
// Per-chunk output via MFMA (round-6 verbatim).
// ---------------------------------------------------------------------------
__global__ __launch_bounds__(256) void k_out_chunk(
    const ushort* __restrict__ Qg, const ushort* __restrict__ Kg,
    const ushort* __restrict__ Vg, const ushort* __restrict__ Gg,
    const ushort* __restrict__ Sst, const float* __restrict__ Zst,
    ushort* __restrict__ Op)
{
    __shared__ ushort VT[64 * 40];
    __shared__ ushort Pb[32 * 40];
    __shared__ float zinv[32];

    const int blk = blockIdx.x;
    const int bh = blk >> 5, g = blk & 31;
    const int b = bh >> 3, h = bh & 7;
    const int tid = threadIdx.x;
    const int rBase = b * T_ + g * C_;
    const int colB = h * DK_;
    const int wave = tid >> 6, lane = tid & 63;
    const int q = lane >> 4, ln = lane & 15;

    {
        int row = tid >> 3, c8 = (tid & 7) * 8;
        uint4 vraw = *(const uint4*)&Vg[(size_t)(rBase + row) * D_ + colB + c8];
        const ushort* vp = (const ushort*)&vraw;
#pragma unroll
        for (int u = 0; u < 8; u++) VT[(c8 + u) * 40 + row] = vp[u];
    }

    const int mi = wave >> 1, njp = wave & 1;
    const ushort* qrow = Qg + (size_t)(rBase + mi * 16 + ln) * D_ + colB;
    s16x8 aq0 = *(const s16x8*)&qrow[q * 8];
    s16x8 aq1 = *(const s16x8*)&qrow[32 + q * 8];
    {
        const ushort* krow = Kg + (size_t)(rBase + njp * 16 + ln) * D_ + colB;
        s16x8 bk0 = *(const s16x8*)&krow[q * 8];
        s16x8 bk1 = *(const s16x8*)&krow[32 + q * 8];
        f32x4 pacc = __builtin_amdgcn_mfma_f32_16x16x32_bf16(
            aq0, bk0, (f32x4){0.f, 0.f, 0.f, 0.f}, 0, 0, 0);
        pacc = __builtin_amdgcn_mfma_f32_16x16x32_bf16(aq1, bk1, pacc, 0, 0, 0);
        int sl = njp * 16 + ln;
        float as_ = (float)(g * C_ + sl) * PI_OVER_2T;
        float cs_ = cosf(as_), ss_ = sinf(as_);
#pragma unroll
        for (int r = 0; r < 4; r++) {
            int tl = mi * 16 + q * 4 + r;
            float at = (float)(g * C_ + tl) * PI_OVER_2T;
            float w = (sl <= tl) ? (cosf(at) * cs_ + sinf(at) * ss_) : 0.f;
            Pb[tl * 40 + sl] = f2bf(pacc[r] * w);
        }
    }
    __syncthreads();

    {
        int t = tid >> 3, sub = tid & 7;
        uint4 qraw = *(const uint4*)&Qg[(size_t)(rBase + t) * D_ + colB + sub * 8];
        const ushort* qp = (const ushort*)&qraw;
        const float* zcp = Zst + (size_t)blk * 128 + sub * 8;
        float4 zc0 = *(const float4*)&zcp[0];
        float4 zc1 = *(const float4*)&zcp[4];
        float4 zs0 = *(const float4*)&zcp[64];
        float4 zs1 = *(const float4*)&zcp[68];
        float pc = 0.f, ps = 0.f;
        float zcv[8] = {zc0.x, zc0.y, zc0.z, zc0.w, zc1.x, zc1.y, zc1.z, zc1.w};
        float zsv[8] = {zs0.x, zs0.y, zs0.z, zs0.w, zs1.x, zs1.y, zs1.z, zs1.w};
#pragma unroll
        for (int u = 0; u < 8; u++) {
            float qf = bf2f(qp[u]);
            pc += qf * zcv[u]; ps += qf * zsv[u];
        }
        float pr = 0.f;
#pragma unroll
        for (int u = 0; u < 4; u++) pr += bf2f(Pb[t * 40 + sub * 4 + u]);
#pragma unroll
        for (int m = 1; m < 8; m <<= 1) {
            pc += __shfl_xor(pc, m);
            ps += __shfl_xor(ps, m);
            pr += __shfl_xor(pr, m);
        }
        if (sub == 0) {
            float at = (float)(g * C_ + t) * PI_OVER_2T;
            float z = cosf(at) * pc + sinf(at) * ps + pr;
            zinv[t] = 1.f / fmaxf(z, 1e-6f);
        }
    }
    __syncthreads();

    {
        float am = (float)(g * C_ + mi * 16 + ln) * PI_OVER_2T;
        float cm = cosf(am), sm_ = sinf(am);
        s16x8 aqc0 = bscale(aq0, cm), aqc1 = bscale(aq1, cm);
        s16x8 aqs0 = bscale(aq0, sm_), aqs1 = bscale(aq1, sm_);
        s16x8 pf = *(const s16x8*)&Pb[(mi * 16 + ln) * 40 + q * 8];
        const ushort* Sp = Sst + (size_t)blk * 8192;
#pragma unroll
        for (int jj = 0; jj < 2; jj++) {
            int nj = 2 * (wave & 1) + jj;
            const ushort* scp = Sp + (nj * 16 + ln) * 64;
            s16x8 bc0 = *(const s16x8*)&scp[q * 8];
            s16x8 bc1 = *(const s16x8*)&scp[32 + q * 8];
            s16x8 bs0 = *(const s16x8*)&scp[4096 + q * 8];
            s16x8 bs1 = *(const s16x8*)&scp[4096 + 32 + q * 8];
            s16x8 bv  = *(const s16x8*)&VT[(nj * 16 + ln) * 40 + q * 8];
            f32x4 acc = __builtin_amdgcn_mfma_f32_16x16x32_bf16(
                pf, bv, (f32x4){0.f, 0.f, 0.f, 0.f}, 0, 0, 0);
            acc = __builtin_amdgcn_mfma_f32_16x16x32_bf16(aqc0, bc0, acc, 0, 0, 0);
            acc = __builtin_amdgcn_mfma_f32_16x16x32_bf16(aqc1, bc1, acc, 0, 0, 0);
            acc = __builtin_amdgcn_mfma_f32_16x16x32_bf16(aqs0, bs0, acc, 0, 0, 0);
            acc = __builtin_amdgcn_mfma_f32_16x16x32_bf16(aqs1, bs1, acc, 0, 0, 0);
#pragma unroll
            for (int r = 0; r < 4; r++) {
                int tl = mi * 16 + q * 4 + r;
                int e = nj * 16 + ln;
                size_t go = (size_t)(rBase + tl) * D_ + colB + e;
                float o = acc[r] * zinv[tl] * bf2f(Gg[go]);
                Op[go] = f2bf(o);
            }
        }
    }
}

// ---------------------------------------------------------------------------
extern "C" void kernel_launch(void* const* d_in, const int* in_sizes, int n_in,
                              void* d_out, int out_size, void* d_ws, size_t ws_size,
                              hipStream_t stream)
{
    const float* x  = (const float*)d_in[0];
    const float* Wq = (const float*)d_in[1];
    const float* Wk = (const float*)d_in[2];
    const float* Wv = (const float*)d_in[3];
    const float* Wo = (const float*)d_in[4];
    const float* Wg = (const float*)d_in[5];
    const float* bg = (const float*)d_in[6];
    float* out = (float*)d_out;

    ushort* wsu = (ushort*)d_ws;
    ushort* xb    = wsu;                   // 1M bf16
    ushort* WtAll = xb + 1048576;          // 5*256K bf16
    ushort* Qg    = WtAll + 1310720;       // 1M bf16 each
    ushort* Kg    = Qg + 1048576;
    ushort* Vg    = Kg + 1048576;
    ushort* Gg    = Vg + 1048576;
    ushort* Sst   = Gg + 1048576;          // 4M bf16 (ScT/SsT per chunk)
    ushort* Opb   = Sst + 4194304;         // 1M bf16
    float*  Zst   = (float*)(Opb + 1048576);  // 64K f32

    dim3 blk(256);
    k_conv<<<dim3(1344), blk, 0, stream>>>(x, Wq, Wk, Wv, Wg, Wo, xb, WtAll);
    k_g0<<<dim3(16, 32), blk, 0, stream>>>(
        xb, WtAll, bg, Qg, Kg, Vg, Gg, Sst, Zst);
    k_scan<<<dim3(130), blk, 0, stream>>>(Sst, Zst);
    k_out_chunk<<<dim3(NBH_ * G_), blk, 0, stream>>>(
        Qg, Kg, Vg, Gg, Sst, Zst, Opb);
    k_gemm<1, 64, 64, 64><<<dim3(8, 32), blk, 0, stream>>>(
        Opb, WtAll + (size_t)4 * 262144, nullptr,
        out, nullptr, nullptr, nullptr);
}

// Round 9
// 103.417 us; speedup vs baseline: 8.0069x; 1.0139x over previous
//
#include <hip/hip_runtime.h>
#include <math.h>

// Problem constants
#define B_ 2
#define T_ 1024
#define D_ 512
#define H_ 8
#define DK_ 64
#define NBH_ 16          // B*H
#define C_ 32            // chunk length
#define G_ 32            // T/C chunks

#define PI_OVER_2T 0.00153398078788564122971808758949f  /* pi/2048 */

typedef float f32x4 __attribute__((ext_vector_type(4)));
typedef short s16x8 __attribute__((ext_vector_type(8)));

__device__ __forceinline__ ushort f2bf(float x) {
    unsigned u = __float_as_uint(x);
    unsigned r = (u + 0x7fffu + ((u >> 16) & 1u)) >> 16;   // RNE
    return (ushort)r;
}
__device__ __forceinline__ float bf2f(ushort u) {
    return __uint_as_float((unsigned)u << 16);
}
__device__ __forceinline__ s16x8 bscale(s16x8 v, float s) {
    s16x8 r;
#pragma unroll
    for (int u = 0; u < 8; u++)
        r[u] = (short)f2bf(bf2f((ushort)v[u]) * s);
    return r;
}

// async global->LDS, 16B/lane; LDS dest must be tid-contiguous (m104).
__device__ __forceinline__ void async16(void* lds, const void* g) {
    __builtin_amdgcn_global_load_lds(
        (const __attribute__((address_space(1))) void*)g,
        (__attribute__((address_space(3))) void*)lds, 16, 0, 0);
}

// ---------------------------------------------------------------------------
// Fused convert kernel (round-6 verbatim).
// blocks 0..1023: x -> xb bf16.  1024..1343: 5 weights -> WtAll bf16 (n,k).
// ---------------------------------------------------------------------------
__global__ __launch_bounds__(256) void k_conv(
    const float* __restrict__ x,
    const float* __restrict__ Wq, const float* __restrict__ Wk,
    const float* __restrict__ Wv, const float* __restrict__ Wg,
    const float* __restrict__ Wo,
    ushort* __restrict__ xb, ushort* __restrict__ WtAll)
{
    __shared__ float Ts[64][65];
    const int bx = blockIdx.x;
    const int tid = threadIdx.x;
    if (bx < 1024) {
        int i = (bx * 256 + tid) * 4;
        float4 v = *(const float4*)&x[i];
        ushort4 o;
        o.x = f2bf(v.x); o.y = f2bf(v.y); o.z = f2bf(v.z); o.w = f2bf(v.w);
        *(ushort4*)&xb[i] = o;
        return;
    }
    const int bid = bx - 1024;
    const int mi = bid >> 6;
    const int t64 = bid & 63;
    const float* __restrict__ W = (mi == 0) ? Wq : (mi == 1) ? Wk
                                 : (mi == 2) ? Wv : (mi == 3) ? Wg : Wo;
    const int tr = t64 >> 3, tc = t64 & 7;
#pragma unroll
    for (int p = 0; p < 4; p++) {
        int row = p * 16 + (tid >> 4);
        int c4 = (tid & 15) * 4;
        float4 v = *(const float4*)&W[(size_t)(tr * 64 + row) * 512 + tc * 64 + c4];
        Ts[row][c4 + 0] = v.x; Ts[row][c4 + 1] = v.y;
        Ts[row][c4 + 2] = v.z; Ts[row][c4 + 3] = v.w;
    }
    __syncthreads();
    const int nl = tid >> 2, kc = (tid & 3) * 16;
    ushort buf[16];
#pragma unroll
    for (int u = 0; u < 16; u++) buf[u] = f2bf(Ts[kc + u][nl]);
    ushort* dst = WtAll + (size_t)mi * 262144 + (size_t)(tc * 64 + nl) * 512
                  + tr * 64 + kc;
    *(uint4*)dst = *(uint4*)&buf[0];
    *(uint4*)(dst + 8) = *(uint4*)&buf[8];
}

// ---------------------------------------------------------------------------
// FUSED dual-matrix projection GEMM + per-chunk KV state epilogue
// (round-8 verbatim — matched prediction, keep).
// ---------------------------------------------------------------------------
__global__ __launch_bounds__(256) void k_g0(
    const ushort* __restrict__ A, const ushort* __restrict__ WtAll,
    const float* __restrict__ bg,
    ushort* __restrict__ Qg, ushort* __restrict__ Kg,
    ushort* __restrict__ Vg, ushort* __restrict__ Gg,
    ushort* __restrict__ Sst, float* __restrict__ Zst)
{
    __shared__ union {
        struct { ushort As[2][64 * 64]; ushort Bs[2][2 * 64 * 64]; } s; // 48 KB
        struct { ushort KcT[64 * 72]; ushort KsT[64 * 72];
                 ushort VT[64 * 72]; } e;                               // 27 KB
    } sm;

    const int tid = threadIdx.x;
    const int ct = blockIdx.x;
    const int rowBase = blockIdx.y * 64;
    const bool isKV = (ct >= 8);
    const int matCol = (ct & 7) * 64;
    const ushort* __restrict__ B0 = WtAll + (size_t)(isKV ? 1 : 0) * 262144;
    const ushort* __restrict__ B1 = WtAll + (size_t)(isKV ? 2 : 3) * 262144;

    const int wave = tid >> 6, lane = tid & 63;
    const int q = lane >> 4, ln = lane & 15;
    const int mB = (wave >> 1) * 32, nB = (wave & 1) * 32;

    int fu[2];
    const ushort* gA[2];
    const ushort* gB0[2];
    const ushort* gB1[2];
#pragma unroll
    for (int u = 0; u < 2; u++) {
        int f = tid * 8 + u * 2048;
        int r = f >> 6;
        int gc = ((f >> 3) & 7) ^ (r & 7);
        fu[u] = f;
        gA[u]  = A  + (size_t)(rowBase + r) * 512 + gc * 8;
        gB0[u] = B0 + (size_t)(matCol + r) * 512 + gc * 8;
        gB1[u] = B1 + (size_t)(matCol + r) * 512 + gc * 8;
    }

    f32x4 accA[2][2], accB[2][2];
#pragma unroll
    for (int i = 0; i < 2; i++)
#pragma unroll
        for (int j = 0; j < 2; j++) {
            accA[i][j] = (f32x4){0.f, 0.f, 0.f, 0.f};
            accB[i][j] = (f32x4){0.f, 0.f, 0.f, 0.f};
        }

    int aoff[2][2], boff[2][2];
#pragma unroll
    for (int i = 0; i < 2; i++) {
        int ra = mB + i * 16 + ln;
#pragma unroll
        for (int ks = 0; ks < 2; ks++)
            aoff[i][ks] = ra * 64 + (((ks * 4 + q) ^ (ra & 7)) * 8);
    }
#pragma unroll
    for (int j = 0; j < 2; j++) {
        int rb = nB + j * 16 + ln;
#pragma unroll
        for (int ks = 0; ks < 2; ks++)
            boff[j][ks] = rb * 64 + (((ks * 4 + q) ^ (rb & 7)) * 8);
    }

#pragma unroll
    for (int u = 0; u < 2; u++) {
        async16(&sm.s.As[0][fu[u]], gA[u]);
        async16(&sm.s.Bs[0][fu[u]], gB0[u]);
        async16(&sm.s.Bs[0][4096 + fu[u]], gB1[u]);
    }

    int cur = 0;
    for (int kb = 0; kb < 512; kb += 64) {
        __syncthreads();
        if (kb + 64 < 512) {
            int nxt = cur ^ 1;
#pragma unroll
            for (int u = 0; u < 2; u++) {
                async16(&sm.s.As[nxt][fu[u]], gA[u] + kb + 64);
                async16(&sm.s.Bs[nxt][fu[u]], gB0[u] + kb + 64);
                async16(&sm.s.Bs[nxt][4096 + fu[u]], gB1[u] + kb + 64);
            }
        }
#pragma unroll
        for (int ks = 0; ks < 2; ks++) {
            s16x8 af[2], b0f[2], b1f[2];
#pragma unroll
            for (int i = 0; i < 2; i++)
                af[i] = *(const s16x8*)&sm.s.As[cur][aoff[i][ks]];
#pragma unroll
            for (int j = 0; j < 2; j++) {
                b0f[j] = *(const s16x8*)&sm.s.Bs[cur][boff[j][ks]];
                b1f[j] = *(const s16x8*)&sm.s.Bs[cur][4096 + boff[j][ks]];
            }
#pragma unroll
            for (int i = 0; i < 2; i++)
#pragma unroll
                for (int j = 0; j < 2; j++) {
                    accA[i][j] = __builtin_amdgcn_mfma_f32_16x16x32_bf16(
                        af[i], b0f[j], accA[i][j], 0, 0, 0);
                    accB[i][j] = __builtin_amdgcn_mfma_f32_16x16x32_bf16(
                        af[i], b1f[j], accB[i][j], 0, 0, 0);
                }
        }
        cur ^= 1;
    }
    __syncthreads();

    if (!isKV) {
#pragma unroll
        for (int i = 0; i < 2; i++)
#pragma unroll
            for (int j = 0; j < 2; j++) {
                int col = matCol + nB + j * 16 + ln;
#pragma unroll
                for (int r = 0; r < 4; r++) {
                    int row = rowBase + mB + i * 16 + q * 4 + r;
                    Qg[(size_t)row * 512 + col] = f2bf(fmaxf(accA[i][j][r], 0.f));
                    Gg[(size_t)row * 512 + col] =
                        f2bf(1.f / (1.f + expf(-(accB[i][j][r] + bg[col]))));
                }
            }
        return;
    }

    // ---- KV epilogue ----
    const int h = ct - 8;
    const int b = rowBase >> 10;
    const int c = wave >> 1;
    const int gG = ((rowBase & 1023) >> 5) + c;
    const int blk = (b * 8 + h) * 32 + gG;

    float zc[2] = {0.f, 0.f}, zs[2] = {0.f, 0.f};
#pragma unroll
    for (int i = 0; i < 2; i++)
#pragma unroll
        for (int r = 0; r < 4; r++) {
            int tLoc = mB + i * 16 + q * 4 + r;
            int rowG = rowBase + tLoc;
            float a = (float)(rowG & 1023) * PI_OVER_2T;
            float ca = cosf(a), sa = sinf(a);
#pragma unroll
            for (int j = 0; j < 2; j++) {
                int col = nB + j * 16 + ln;
                float kv = fmaxf(accA[i][j][r], 0.f);
                float vv = accB[i][j][r];
                size_t go = (size_t)rowG * 512 + h * 64 + col;
                Kg[go] = f2bf(kv);
                Vg[go] = f2bf(vv);
                float kc = kv * ca, ks = kv * sa;
                sm.e.KcT[col * 72 + tLoc] = f2bf(kc);
                sm.e.KsT[col * 72 + tLoc] = f2bf(ks);
                sm.e.VT [col * 72 + tLoc] = f2bf(vv);
                zc[j] += kc; zs[j] += ks;
            }
        }
#pragma unroll
    for (int j = 0; j < 2; j++) {
        zc[j] += __shfl_xor(zc[j], 16); zc[j] += __shfl_xor(zc[j], 32);
        zs[j] += __shfl_xor(zs[j], 16); zs[j] += __shfl_xor(zs[j], 32);
    }
    if (q == 0) {
#pragma unroll
        for (int j = 0; j < 2; j++) {
            int d = nB + j * 16 + ln;
            Zst[(size_t)blk * 128 + d] = zc[j];
            Zst[(size_t)blk * 128 + 64 + d] = zs[j];
        }
    }
    __syncthreads();

    {
        const int eh = (wave & 1) * 32;
        ushort* Sp = Sst + (size_t)blk * 8192;
        s16x8 av[2];
#pragma unroll
        for (int fi = 0; fi < 2; fi++)
            av[fi] = *(const s16x8*)&sm.e.VT[(eh + fi * 16 + ln) * 72
                                            + c * 32 + q * 8];
#pragma unroll
        for (int fj = 0; fj < 4; fj++) {
            s16x8 bc = *(const s16x8*)&sm.e.KcT[(fj * 16 + ln) * 72
                                                + c * 32 + q * 8];
            s16x8 bs = *(const s16x8*)&sm.e.KsT[(fj * 16 + ln) * 72
                                                + c * 32 + q * 8];
#pragma unroll
            for (int fi = 0; fi < 2; fi++) {
                f32x4 sc = __builtin_amdgcn_mfma_f32_16x16x32_bf16(
                    av[fi], bc, (f32x4){0.f, 0.f, 0.f, 0.f}, 0, 0, 0);
                f32x4 ss = __builtin_amdgcn_mfma_f32_16x16x32_bf16(
                    av[fi], bs, (f32x4){0.f, 0.f, 0.f, 0.f}, 0, 0, 0);
#pragma unroll
                for (int rr = 0; rr < 4; rr++) {
                    int e = eh + fi * 16 + q * 4 + rr;
                    int d = fj * 16 + ln;
                    Sp[e * 64 + d] = f2bf(sc[rr]);
                    Sp[4096 + e * 64 + d] = f2bf(ss[rr]);
                }
            }
        }
    }
}

// ---------------------------------------------------------------------------
// Out-projection GEMM (MODE 1). Round 9: TN 64->32, grid (16,32)=512 blocks
// = 2 blocks/CU (was 256 = 1/CU) for latency hiding.
// ---------------------------------------------------------------------------
template<int MODE, int TM, int TN, int BK>
__global__ __launch_bounds__(256) void k_gemm(
    const ushort* __restrict__ A, const ushort* __restrict__ Bt,
    const float* __restrict__ bg,
    void* __restrict__ O0v, void* __restrict__ O1v,
    void* __restrict__ O2v, void* __restrict__ O3v)
{
    constexpr int WM = TM / 2, WN = TN / 2;
    constexpr int FM = WM / 16, FN = WN / 16;
    constexpr int CH = BK / 8;
    constexpr int SH = (BK == 32) ? 1 : 0;
    constexpr int KS = BK / 32;
    constexpr int NA = TM * BK / 2048;
    constexpr int NB = TN * BK / 2048;

    __shared__ ushort As[2][TM * BK];
    __shared__ ushort Bs[2][TN * BK];

    const int tid = threadIdx.x;
    const int ct = blockIdx.x;
    const int rowBase = blockIdx.y * TM;

    const int matCol = ct * TN;
    const ushort* __restrict__ Bmat = Bt;

    const int wave = tid >> 6, lane = tid & 63;
    const int q = lane >> 4, ln = lane & 15;
    const int mB = (wave >> 1) * WM, nB = (wave & 1) * WN;

    int fuA[NA], fuB[NB];
    const ushort* gA[NA];
    const ushort* gB[NB];
#pragma unroll
    for (int u = 0; u < NA; u++) {
        int fu = tid * 8 + u * 2048;
        int r = fu / BK;
        int slot = (fu >> 3) & (CH - 1);
        int gc = slot ^ ((r >> SH) & (CH - 1));
        fuA[u] = fu;
        gA[u] = A + (size_t)(rowBase + r) * 512 + gc * 8;
    }
#pragma unroll
    for (int u = 0; u < NB; u++) {
        int fu = tid * 8 + u * 2048;
        int r = fu / BK;
        int slot = (fu >> 3) & (CH - 1);
        int gc = slot ^ ((r >> SH) & (CH - 1));
        fuB[u] = fu;
        gB[u] = Bmat + (size_t)(matCol + r) * 512 + gc * 8;
    }

    f32x4 acc[FM][FN];
#pragma unroll
    for (int i = 0; i < FM; i++)
#pragma unroll
        for (int j = 0; j < FN; j++) acc[i][j] = (f32x4){0.f, 0.f, 0.f, 0.f};

    int aoff[FM][KS], boff[FN][KS];
#pragma unroll
    for (int i = 0; i < FM; i++) {
        int ra = mB + i * 16 + ln;
#pragma unroll
        for (int ks = 0; ks < KS; ks++)
            aoff[i][ks] = ra * BK + (((ks * 4 + q) ^ ((ra >> SH) & (CH - 1))) * 8);
    }
#pragma unroll
    for (int j = 0; j < FN; j++) {
        int rb = nB + j * 16 + ln;
#pragma unroll
        for (int ks = 0; ks < KS; ks++)
            boff[j][ks] = rb * BK + (((ks * 4 + q) ^ ((rb >> SH) & (CH - 1))) * 8);
    }

#pragma unroll
    for (int u = 0; u < NA; u++) async16(&As[0][fuA[u]], gA[u]);
#pragma unroll
    for (int u = 0; u < NB; u++) async16(&Bs[0][fuB[u]], gB[u]);

    int cur = 0;
    for (int kb = 0; kb < 512; kb += BK) {
        __syncthreads();
        if (kb + BK < 512) {
#pragma unroll
            for (int u = 0; u < NA; u++)
                async16(&As[cur ^ 1][fuA[u]], gA[u] + kb + BK);
#pragma unroll
            for (int u = 0; u < NB; u++)
                async16(&Bs[cur ^ 1][fuB[u]], gB[u] + kb + BK);
        }
#pragma unroll
        for (int ks = 0; ks < KS; ks++) {
            s16x8 af[FM], bf[FN];
#pragma unroll
            for (int i = 0; i < FM; i++)
                af[i] = *(const s16x8*)&As[cur][aoff[i][ks]];
#pragma unroll
            for (int j = 0; j < FN; j++)
                bf[j] = *(const s16x8*)&Bs[cur][boff[j][ks]];
#pragma unroll
            for (int i = 0; i < FM; i++)
#pragma unroll
                for (int j = 0; j < FN; j++)
                    acc[i][j] = __builtin_amdgcn_mfma_f32_16x16x32_bf16(
                        af[i], bf[j], acc[i][j], 0, 0, 0);
        }
        cur ^= 1;
    }

    float* __restrict__ Out = (float*)O0v;
#pragma unroll
    for (int i = 0; i < FM; i++)
#pragma unroll
        for (int j = 0; j < FN; j++) {
            int col = matCol + nB + j * 16 + ln;
#pragma unroll
            for (int r = 0; r < 4; r++) {
                int row = rowBase + mB + i * 16 + q * 4 + r;
                Out[(size_t)row * 512 + col] = acc[i][j][r];
            }
        }
}

// ---------------------------------------------------------------------------
// Exclusive chunk-scan, latency-pipelined (round-6 verbatim).
// ---------------------------------------------------------------------------
__global__ __launch_bounds__(256) void k_scan(
    ushort* __restrict__ Sst, float* __restrict__ Zst)
{
    int id = blockIdx.x * 256 + threadIdx.x;
    if (id < 32768) {
        int bh = id >> 11, i4 = (id & 2047) * 4;
        size_t base = (size_t)bh * (G_ * 8192) + i4;
        ushort4 v[G_];
#pragma unroll
        for (int g = 0; g < G_; g++)
            v[g] = *(const ushort4*)&Sst[base + (size_t)g * 8192];
        float rx = 0.f, ry = 0.f, rz = 0.f, rw = 0.f;
#pragma unroll
        for (int g = 0; g < G_; g++) {
            ushort4 t = v[g];
            ushort4 o;
            o.x = f2bf(rx); o.y = f2bf(ry); o.z = f2bf(rz); o.w = f2bf(rw);
            *(ushort4*)&Sst[base + (size_t)g * 8192] = o;
            rx += bf2f(t.x); ry += bf2f(t.y);
            rz += bf2f(t.z); rw += bf2f(t.w);
        }
    } else {
        int id2 = id - 32768;
        if (id2 >= 512) return;
        int bh = id2 >> 5, i4 = (id2 & 31) * 4;
        size_t base = (size_t)bh * (G_ * 128) + i4;
        float4 v[G_];
#pragma unroll
        for (int g = 0; g < G_; g++)
            v[g] = *(const float4*)&Zst[base + (size_t)g * 128];
        float4 run = make_float4(0.f, 0.f, 0.f, 0.f);
#pragma unroll
        for (int g = 0; g < G_; g++) {
            float4 t = v[g];
            *(float4*)&Zst[base + (size_t)g * 128] = run;
            run.x += t.x; run.y += t.y; run.z += t.z; run.w += t.w;
        }
    }
}

// ---------------------------------------------------------------------------
// Per-chunk output via MFMA (round-6 verbatim).
// ---------------------------------------------------------------------------
__global__ __launch_bounds__(256) void k_out_chunk(
    const ushort* __restrict__ Qg, const ushort* __restrict__ Kg,
    const ushort* __restrict__ Vg, const ushort* __restrict__ Gg,
    const ushort* __restrict__ Sst, const float* __restrict__ Zst,
    ushort* __restrict__ Op)
{
    __shared__ ushort VT[64 * 40];
    __shared__ ushort Pb[32 * 40];
    __shared__ float zinv[32];

    const int blk = blockIdx.x;
    const int bh = blk >> 5, g = blk & 31;
    const int b = bh >> 3, h = bh & 7;
    const int tid = threadIdx.x;
    const int rBase = b * T_ + g * C_;
    const int colB = h * DK_;
    const int wave = tid >> 6, lane = tid & 63;
    const int q = lane >> 4, ln = lane & 15;

    {
        int row = tid >> 3, c8 = (tid & 7) * 8;
        uint4 vraw = *(const uint4*)&Vg[(size_t)(rBase + row) * D_ + colB + c8];
        const ushort* vp = (const ushort*)&vraw;
#pragma unroll
        for (int u = 0; u < 8; u++) VT[(c8 + u) * 40 + row] = vp[u];
    }

    const int mi = wave >> 1, njp = wave & 1;
    const ushort* qrow = Qg + (size_t)(rBase + mi * 16 + ln) * D_ + colB;
    s16x8 aq0 = *(const s16x8*)&qrow[q * 8];
    s16x8 aq1 = *(const s16x8*)&qrow[32 + q * 8];
    {
        const ushort* krow = Kg + (size_t)(rBase + njp * 16 + ln) * D_ + colB;
        s16x8 bk0 = *(const s16x8*)&krow[q * 8];
        s16x8 bk1 = *(const s16x8*)&krow[32 + q * 8];
        f32x4 pacc = __builtin_amdgcn_mfma_f32_16x16x32_bf16(
            aq0, bk0, (f32x4){0.f, 0.f, 0.f, 0.f}, 0, 0, 0);
        pacc = __builtin_amdgcn_mfma_f32_16x16x32_bf16(aq1, bk1, pacc, 0, 0, 0);
        int sl = njp * 16 + ln;
        float as_ = (float)(g * C_ + sl) * PI_OVER_2T;
        float cs_ = cosf(as_), ss_ = sinf(as_);
#pragma unroll
        for (int r = 0; r < 4; r++) {
            int tl = mi * 16 + q * 4 + r;
            float at = (float)(g * C_ + tl) * PI_OVER_2T;
            float w = (sl <= tl) ? (cosf(at) * cs_ + sinf(at) * ss_) : 0.f;
            Pb[tl * 40 + sl] = f2bf(pacc[r] * w);
        }
    }
    __syncthreads();

    {
        int t = tid >> 3, sub = tid & 7;
        uint4 qraw = *(const uint4*)&Qg[(size_t)(rBase + t) * D_ + colB + sub * 8];
        const ushort* qp = (const ushort*)&qraw;
        const float* zcp = Zst + (size_t)blk * 128 + sub * 8;
        float4 zc0 = *(const float4*)&zcp[0];
        float4 zc1 = *(const float4*)&zcp[4];
        float4 zs0 = *(const float4*)&zcp[64];
        float4 zs1 = *(const float4*)&zcp[68];
        float pc = 0.f, ps = 0.f;
        float zcv[8] = {zc0.x, zc0.y, zc0.z, zc0.w, zc1.x, zc1.y, zc1.z, zc1.w};
        float zsv[8] = {zs0.x, zs0.y, zs0.z, zs0.w, zs1.x, zs1.y, zs1.z, zs1.w};
#pragma unroll
        for (int u = 0; u < 8; u++) {
            float qf = bf2f(qp[u]);
            pc += qf * zcv[u]; ps += qf * zsv[u];
        }
        float pr = 0.f;
#pragma unroll
        for (int u = 0; u < 4; u++) pr += bf2f(Pb[t * 40 + sub * 4 + u]);
#pragma unroll
        for (int m = 1; m < 8; m <<= 1) {
            pc += __shfl_xor(pc, m);
            ps += __shfl_xor(ps, m);
            pr += __shfl_xor(pr, m);
        }
        if (sub == 0) {
            float at = (float)(g * C_ + t) * PI_OVER_2T;
            float z = cosf(at) * pc + sinf(at) * ps + pr;
            zinv[t] = 1.f / fmaxf(z, 1e-6f);
        }
    }
    __syncthreads();

    {
        float am = (float)(g * C_ + mi * 16 + ln) * PI_OVER_2T;
        float cm = cosf(am), sm_ = sinf(am);
        s16x8 aqc0 = bscale(aq0, cm), aqc1 = bscale(aq1, cm);
        s16x8 aqs0 = bscale(aq0, sm_), aqs1 = bscale(aq1, sm_);
        s16x8 pf = *(const s16x8*)&Pb[(mi * 16 + ln) * 40 + q * 8];
        const ushort* Sp = Sst + (size_t)blk * 8192;
#pragma unroll
        for (int jj = 0; jj < 2; jj++) {
            int nj = 2 * (wave & 1) + jj;
            const ushort* scp = Sp + (nj * 16 + ln) * 64;
            s16x8 bc0 = *(const s16x8*)&scp[q * 8];
            s16x8 bc1 = *(const s16x8*)&scp[32 + q * 8];
            s16x8 bs0 = *(const s16x8*)&scp[4096 + q * 8];
            s16x8 bs1 = *(const s16x8*)&scp[4096 + 32 + q * 8];
            s16x8 bv  = *(const s16x8*)&VT[(nj * 16 + ln) * 40 + q * 8];
            f32x4 acc = __builtin_amdgcn_mfma_f32_16x16x32_bf16(
                pf, bv, (f32x4){0.f, 0.f, 0.f, 0.f}, 0, 0, 0);
            acc = __builtin_amdgcn_mfma_f32_16x16x32_bf16(aqc0, bc0, acc, 0, 0, 0);
            acc = __builtin_amdgcn_mfma_f32_16x16x32_bf16(aqc1, bc1, acc, 0, 0, 0);
            acc = __builtin_amdgcn_mfma_f32_16x16x32_bf16(aqs0, bs0, acc, 0, 0, 0);
            acc = __builtin_amdgcn_mfma_f32_16x16x32_bf16(aqs1, bs1, acc, 0, 0, 0);
#pragma unroll
            for (int r = 0; r < 4; r++) {
                int tl = mi * 16 + q * 4 + r;
                int e = nj * 16 + ln;
                size_t go = (size_t)(rBase + tl) * D_ + colB + e;
                float o = acc[r] * zinv[tl] * bf2f(Gg[go]);
                Op[go] = f2bf(o);
            }
        }
    }
}

// ---------------------------------------------------------------------------
extern "C" void kernel_launch(void* const* d_in, const int* in_sizes, int n_in,
                              void* d_out, int out_size, void* d_ws, size_t ws_size,
                              hipStream_t stream)
{
    const float* x  = (const float*)d_in[0];
    const float* Wq = (const float*)d_in[1];
    const float* Wk = (const float*)d_in[2];
    const float* Wv = (const float*)d_in[3];
    const float* Wo = (const float*)d_in[4];
    const float* Wg = (const float*)d_in[5];
    const float* bg = (const float*)d_in[6];
    float* out = (float*)d_out;

    ushort* wsu = (ushort*)d_ws;
    ushort* xb    = wsu;                   // 1M bf16
    ushort* WtAll = xb + 1048576;          // 5*256K bf16
    ushort* Qg    = WtAll + 1310720;       // 1M bf16 each
    ushort* Kg    = Qg + 1048576;
    ushort* Vg    = Kg + 1048576;
    ushort* Gg    = Vg + 1048576;
    ushort* Sst   = Gg + 1048576;          // 4M bf16 (ScT/SsT per chunk)
    ushort* Opb   = Sst + 4194304;         // 1M bf16
    float*  Zst   = (float*)(Opb + 1048576);  // 64K f32

    dim3 blk(256);
    k_conv<<<dim3(1344), blk, 0, stream>>>(x, Wq, Wk, Wv, Wg, Wo, xb, WtAll);
    k_g0<<<dim3(16, 32), blk, 0, stream>>>(
        xb, WtAll, bg, Qg, Kg, Vg, Gg, Sst, Zst);
    k_scan<<<dim3(130), blk, 0, stream>>>(Sst, Zst);
    k_out_chunk<<<dim3(NBH_ * G_), blk, 0, stream>>>(
        Qg, Kg, Vg, Gg, Sst, Zst, Opb);
    k_gemm<1, 64, 32, 64><<<dim3(16, 32), blk, 0, stream>>>(
        Opb, WtAll + (size_t)4 * 262144, nullptr,
        out, nullptr, nullptr, nullptr);
}